// Round 11
// baseline (162.506 us; speedup 1.0000x reference)
//
#include <hip/hip_runtime.h>
#include <hip/hip_fp16.h>
#include <math.h>

#define N_NODES 100000
#define N_EDGES 1000000
#define SLOTS 64                              // per-node csr slots (max deg ~30)
#define QKV_BLOCKS ((N_NODES + 63) / 64)      // 1563
#define FILL_BLOCKS ((N_EDGES + 1023) / 1024) // 977 (4 edges/thread)
#define PREP_BLOCKS 96                        // 24576 weight elems / 256
#define ZERO_BLOCKS 98                        // 100000/4 int4-stores / 256
#define AGG_BLOCKS (N_NODES / 16)             // 6250
// IN=64, TD=64, OUT=64, H=4, HD=16

typedef __attribute__((ext_vector_type(8))) _Float16 f16x8;
typedef __attribute__((ext_vector_type(4))) float    f32x4;

// ---------------------------------------------------------------------------
// Dispatch 1: weight transpose+fp16 (96 blocks) + zero cnt (98 blocks).
// WqT/WkT: [64][128]; WvT/WoT: [64][64]. WT[c][k] = w[k*64+c].
// ---------------------------------------------------------------------------
__global__ __launch_bounds__(256) void prep_zero_kernel(
    const float* __restrict__ qw, const float* __restrict__ kw,
    const float* __restrict__ vw, const float* __restrict__ ow,
    _Float16* __restrict__ WqT, _Float16* __restrict__ WkT,
    _Float16* __restrict__ WvT, _Float16* __restrict__ WoT,
    int* __restrict__ cnt)
{
    if (blockIdx.x < PREP_BLOCKS) {
        const int idx = blockIdx.x * 256 + threadIdx.x;   // 0..24575
        if (idx < 8192) {
            const int c = idx >> 7, k = idx & 127;
            WqT[idx] = (_Float16)qw[k * 64 + c];
        } else if (idx < 16384) {
            const int i = idx - 8192, c = i >> 7, k = i & 127;
            WkT[i] = (_Float16)kw[k * 64 + c];
        } else if (idx < 20480) {
            const int i = idx - 16384, c = i >> 6, k = i & 63;
            WvT[i] = (_Float16)vw[k * 64 + c];
        } else {
            const int i = idx - 20480, c = i >> 6, k = i & 63;
            WoT[i] = (_Float16)ow[k * 64 + c];
        }
    } else {
        const int idx = (blockIdx.x - PREP_BLOCKS) * 256 + threadIdx.x;
        if (idx < N_NODES / 4)                  // 100000 % 4 == 0
            ((int4*)cnt)[idx] = make_int4(0, 0, 0, 0);
    }
}

// ---------------------------------------------------------------------------
// Dispatch 2: QKV-MFMA (1563 blocks, FIRST so they grab residency) || fill
// (977 blocks, 4 edges/thread with 4 independent atomic chains). Grid total
// 2540 <= ~2048+retirement, so fill's atomic latency hides under qkv compute.
// qkv: block = 64 nodes, 4 waves; wave w owns col tile w of Q, K, V.
// A-tile [64][128] f16 LDS, group j of row r stored at j^(r&15).
// Layouts (m89-verified): A row=lane&15, k=(lane>>4)*8+j ; B col=lane&15,
// same k ; D col=lane&15, row=(lane>>4)*4+reg.
// ---------------------------------------------------------------------------
__global__ __launch_bounds__(256) void fill_qkv_kernel(
    const int* __restrict__ src, const int* __restrict__ dst,
    int* __restrict__ cnt, int* __restrict__ csr_src,
    const float* __restrict__ x, const float* __restrict__ tf,
    const _Float16* __restrict__ WqT, const _Float16* __restrict__ WkT,
    const _Float16* __restrict__ WvT,
    const float* __restrict__ qb, const float* __restrict__ kb,
    const float* __restrict__ vb,
    float* __restrict__ Q, _Float16* __restrict__ Kh, _Float16* __restrict__ Vh)
{
    __shared__ _Float16 xt[64][128];     // 16 KB (fill blocks ignore it)
    const int t = threadIdx.x;

    if (blockIdx.x >= QKV_BLOCKS) {
        // ---- fill role: 4 edges per thread, independent chains ----
        const int e0 = (blockIdx.x - QKV_BLOCKS) * 1024 + t;
        #pragma unroll
        for (int i = 0; i < 4; ++i) {
            const int e = e0 + i * 256;
            if (e < N_EDGES) {
                const int d = dst[e];
                const int pos = atomicAdd(&cnt[d], 1);
                if (pos < SLOTS) csr_src[d * SLOTS + pos] = src[e];
            }
        }
        return;
    }

    const int base = blockIdx.x * 64;

    // stage [x|tf] -> LDS f16, swizzled groups
    {
        const int j = t & 15;
        #pragma unroll
        for (int i = 0; i < 4; ++i) {
            const int r = (t >> 4) + 16 * i;
            int node = base + r;
            if (node >= N_NODES) node = N_NODES - 1;   // clamp; stores guarded
            const float* p = (j < 8) ? (x  + (size_t)node * 64 + 8 * j)
                                     : (tf + (size_t)node * 64 + 8 * (j - 8));
            const float4 lo = ((const float4*)p)[0];
            const float4 hi = ((const float4*)p)[1];
            f16x8 h = { (_Float16)lo.x, (_Float16)lo.y, (_Float16)lo.z,
                        (_Float16)lo.w, (_Float16)hi.x, (_Float16)hi.y,
                        (_Float16)hi.z, (_Float16)hi.w };
            const int js = j ^ (r & 15);
            *(f16x8*)&xt[r][js * 8] = h;
        }
    }

    const int wave = t >> 6;
    const int lane = t & 63;
    const int lrow = lane & 15;
    const int lgrp = lane >> 4;
    const int cw   = wave * 16;

    f16x8 bq[4], bk[4], bv[2];
    const float biasq = qb[cw + lrow];
    const float biask = kb[cw + lrow];
    const float biasv = vb[cw + lrow];
    {
        const size_t rq = (size_t)(cw + lrow) * 128 + lgrp * 8;
        #pragma unroll
        for (int kt = 0; kt < 4; ++kt) {
            bq[kt] = *(const f16x8*)&WqT[rq + kt * 32];
            bk[kt] = *(const f16x8*)&WkT[rq + kt * 32];
        }
        const size_t rv = (size_t)(cw + lrow) * 64 + lgrp * 8;
        #pragma unroll
        for (int kt = 0; kt < 2; ++kt)
            bv[kt] = *(const f16x8*)&WvT[rv + kt * 32];
    }
    __syncthreads();

    #pragma unroll
    for (int rt = 0; rt < 4; ++rt) {
        f16x8 a[4];
        const int r = rt * 16 + lrow;
        #pragma unroll
        for (int kt = 0; kt < 4; ++kt) {
            const int js = (kt * 4 + lgrp) ^ lrow;
            a[kt] = *(const f16x8*)&xt[r][js * 8];
        }
        f32x4 accq = {0.f, 0.f, 0.f, 0.f};
        f32x4 acck = {0.f, 0.f, 0.f, 0.f};
        f32x4 accv = {0.f, 0.f, 0.f, 0.f};
        #pragma unroll
        for (int kt = 0; kt < 4; ++kt) {
            accq = __builtin_amdgcn_mfma_f32_16x16x32_f16(a[kt], bq[kt], accq, 0, 0, 0);
            acck = __builtin_amdgcn_mfma_f32_16x16x32_f16(a[kt], bk[kt], acck, 0, 0, 0);
        }
        #pragma unroll
        for (int kt = 0; kt < 2; ++kt)
            accv = __builtin_amdgcn_mfma_f32_16x16x32_f16(a[kt], bv[kt], accv, 0, 0, 0);
        #pragma unroll
        for (int rr = 0; rr < 4; ++rr) {
            const int node = base + rt * 16 + lgrp * 4 + rr;
            if (node < N_NODES) {
                const size_t o = (size_t)node * 64 + cw + lrow;
                Q [o] = accq[rr] + biasq;
                Kh[o] = (_Float16)(acck[rr] + biask);
                Vh[o] = (_Float16)(accv[rr] + biasv);
            }
        }
    }
}

// ---------------------------------------------------------------------------
// Dispatch 3: gather-aggregate + normalize + MFMA output GEMM, fused.
// Block = 16 nodes, 4 waves; wave processes 4 nodes sequentially (8-edge-slot
// loop, fp16 K/V, 1-deep prefetch), normalized fp16 agg rows -> LDS
// (XOR-swizzled), then out[16x64] = aggh @ WoT via 2 MFMA per wave.
// CSR list for node n: csr_src[n*64 .. n*64+min(cnt[n],64)).
// ---------------------------------------------------------------------------
__global__ __launch_bounds__(256) void agg_kernel(
    const int* __restrict__ cnt, const int* __restrict__ csr_src,
    const float* __restrict__ Q, const __half* __restrict__ Kh,
    const __half* __restrict__ Vh,
    const _Float16* __restrict__ WoT, const float* __restrict__ ob,
    float* __restrict__ out)
{
    __shared__ _Float16 aggh[16][64];     // 2 KB
    const int wave = threadIdx.x >> 6;
    const int lane = threadIdx.x & 63;
    const int g    = lane >> 3;        // edge slot 0..7
    const int s    = lane & 7;         // sublane: cols 8s..8s+7
    const int lrow = lane & 15;        // MFMA A-row / D-col
    const int lgrp = lane >> 4;        // MFMA k-group
    const int nb   = blockIdx.x * 16;  // grid exact: 6250*16

    f16x8 bo0, bo1;
    {
        const size_t ro = (size_t)(wave * 16 + lrow) * 64 + lgrp * 8;
        bo0 = *(const f16x8*)&WoT[ro];
        bo1 = *(const f16x8*)&WoT[ro + 32];
    }
    const float biaso = ob[wave * 16 + lrow];

    const float4* __restrict__ Q4 = (const float4*)Q;
    const uint4*  __restrict__ K4 = (const uint4*)Kh;
    const uint4*  __restrict__ V4 = (const uint4*)Vh;

    for (int nn = 0; nn < 4; ++nn) {
        const int node = nb + wave * 4 + nn;
        const float4 qlo = Q4[(size_t)node * 16 + 2 * s];
        const float4 qhi = Q4[(size_t)node * 16 + 2 * s + 1];
        int d = cnt[node];
        if (d > SLOTS) d = SLOTS;
        const int lo = node * SLOTS;
        const int hi = lo + d;

        float acc[8] = {0.f, 0.f, 0.f, 0.f, 0.f, 0.f, 0.f, 0.f};
        float ssum = 0.f;

        if (lo < hi) {
            int base = lo;
            const int e0 = base + g;
            const int i0 = csr_src[(e0 < hi) ? e0 : (hi - 1)];
            bool act = (e0 < hi);
            uint4 ku = K4[(size_t)i0 * 8 + s];
            uint4 vu = V4[(size_t)i0 * 8 + s];

            while (base < hi) {
                const int nbase = base + 8;
                uint4 kn = make_uint4(0u, 0u, 0u, 0u);
                uint4 vn = make_uint4(0u, 0u, 0u, 0u);
                bool actn = false;
                if (nbase < hi) {                 // prefetch next 8-edge batch
                    const int en = nbase + g;
                    const int in_ = csr_src[(en < hi) ? en : (hi - 1)];
                    kn = K4[(size_t)in_ * 8 + s];
                    vn = V4[(size_t)in_ * 8 + s];
                    actn = (en < hi);
                }
                float kf[8], vf[8];
                {
                    const __half2* kh = (const __half2*)&ku;
                    const __half2* vh = (const __half2*)&vu;
                    #pragma unroll
                    for (int j = 0; j < 4; ++j) {
                        const float2 a = __half22float2(kh[j]);
                        const float2 b = __half22float2(vh[j]);
                        kf[2 * j] = a.x; kf[2 * j + 1] = a.y;
                        vf[2 * j] = b.x; vf[2 * j + 1] = b.y;
                    }
                }
                float dq = qlo.x * kf[0] + qlo.y * kf[1] + qlo.z * kf[2] + qlo.w * kf[3]
                         + qhi.x * kf[4] + qhi.y * kf[5] + qhi.z * kf[6] + qhi.w * kf[7];
                dq += __shfl_xor(dq, 1);          // pair (2h,2h+1): full head dot
                const float p = act ? __expf(dq * 0.25f) : 0.f;   // 1/sqrt(16)
                ssum += p;
                #pragma unroll
                for (int j = 0; j < 8; ++j) acc[j] = fmaf(p, vf[j], acc[j]);
                ku = kn; vu = vn; act = actn; base = nbase;
            }
        }

        // combine the 8 edge slots (lane bits 3,4,5)
        #pragma unroll
        for (int m = 8; m <= 32; m <<= 1) {
            #pragma unroll
            for (int j = 0; j < 8; ++j) acc[j] += __shfl_xor(acc[j], m);
            ssum += __shfl_xor(ssum, m);
        }

        const float inv = (ssum > 0.f) ? (1.0f / ssum) : 0.0f;
        if (g == 0) {
            const int r = wave * 4 + nn;
            f16x8 h = { (_Float16)(acc[0] * inv), (_Float16)(acc[1] * inv),
                        (_Float16)(acc[2] * inv), (_Float16)(acc[3] * inv),
                        (_Float16)(acc[4] * inv), (_Float16)(acc[5] * inv),
                        (_Float16)(acc[6] * inv), (_Float16)(acc[7] * inv) };
            *(f16x8*)&aggh[r][(s ^ (r & 7)) * 8] = h;   // swizzled group
        }
    }
    __syncthreads();

    // out tile [16 nodes][64 cols] = aggh @ WoT ; wave w -> cols 16w..16w+15
    f16x8 a0, a1;
    {
        const int p0 = (lgrp)     ^ (lrow & 7);
        const int p1 = (4 + lgrp) ^ (lrow & 7);
        a0 = *(const f16x8*)&aggh[lrow][p0 * 8];
        a1 = *(const f16x8*)&aggh[lrow][p1 * 8];
    }
    f32x4 acco = {0.f, 0.f, 0.f, 0.f};
    acco = __builtin_amdgcn_mfma_f32_16x16x32_f16(a0, bo0, acco, 0, 0, 0);
    acco = __builtin_amdgcn_mfma_f32_16x16x32_f16(a1, bo1, acco, 0, 0, 0);
    #pragma unroll
    for (int rr = 0; rr < 4; ++rr) {
        const int node = nb + lgrp * 4 + rr;      // D row = lgrp*4+rr
        out[(size_t)node * 64 + wave * 16 + lrow] = acco[rr] + biaso;
    }
}

// ---------------------------------------------------------------------------
extern "C" void kernel_launch(void* const* d_in, const int* in_sizes, int n_in,
                              void* d_out, int out_size, void* d_ws, size_t ws_size,
                              hipStream_t stream) {
    const float* x  = (const float*)d_in[0];
    const float* tf = (const float*)d_in[1];
    const int*   ei = (const int*)  d_in[2];
    const float* qw = (const float*)d_in[3];
    const float* qb = (const float*)d_in[4];
    const float* kw = (const float*)d_in[5];
    const float* kb = (const float*)d_in[6];
    const float* vw = (const float*)d_in[7];
    const float* vb = (const float*)d_in[8];
    const float* ow = (const float*)d_in[9];
    const float* ob = (const float*)d_in[10];
    float* out = (float*)d_out;

    char* ws = (char*)d_ws;
    const size_t qf = (size_t)N_NODES * 64 * sizeof(float);     // 25.6 MB
    const size_t hf = (size_t)N_NODES * 64 * sizeof(_Float16);  // 12.8 MB

    float*    Q       = (float*)(ws);
    _Float16* Kh      = (_Float16*)(ws + qf);
    _Float16* Vh      = (_Float16*)(ws + qf + hf);
    _Float16* WqT     = (_Float16*)(ws + qf + 2 * hf);   // 8192 halves
    _Float16* WkT     = WqT + 8192;                       // 8192
    _Float16* WvT     = WkT + 8192;                       // 4096
    _Float16* WoT     = WvT + 4096;                       // 4096
    int*      cnt     = (int*)(WoT + 4096);               // 100000 ints
    int*      csr_src = cnt + N_NODES;                    // 100000*64 ints

    const int* src = ei;             // edge_index[0]
    const int* dst = ei + N_EDGES;   // edge_index[1]

    const dim3 blk(256);
    prep_zero_kernel<<<dim3(PREP_BLOCKS + ZERO_BLOCKS), blk, 0, stream>>>(
        qw, kw, vw, ow, WqT, WkT, WvT, WoT, cnt);

    fill_qkv_kernel<<<dim3(QKV_BLOCKS + FILL_BLOCKS), blk, 0, stream>>>(
        src, dst, cnt, csr_src,
        x, tf, WqT, WkT, WvT, qb, kb, vb, Q, Kh, Vh);

    agg_kernel<<<dim3(AGG_BLOCKS), blk, 0, stream>>>(
        cnt, csr_src, Q, (const __half*)Kh, (const __half*)Vh, WoT, ob, out);
}

// Round 12
// 160.011 us; speedup vs baseline: 1.0156x; 1.0156x over previous
//
#include <hip/hip_runtime.h>
#include <hip/hip_fp16.h>
#include <math.h>

#define N_NODES 100000
#define N_EDGES 1000000
#define SLOTS 64                              // per-node csr slots (max deg ~25)
#define QKV_BLOCKS ((N_NODES + 63) / 64)      // 1563
#define FILL_BLOCKS ((N_EDGES + 255) / 256)   // 3907 (1 edge/thread)
#define PREP_BLOCKS 96                        // 24576 weight elems / 256
#define ZERO_BLOCKS 1563                      // 100000*16 ints / 4 / 256
#define AGG_BLOCKS (N_NODES / 16)             // 6250
// IN=64, TD=64, OUT=64, H=4, HD=16

typedef __attribute__((ext_vector_type(8))) _Float16 f16x8;
typedef __attribute__((ext_vector_type(4))) float    f32x4;

// ---------------------------------------------------------------------------
// Dispatch 1: weight transpose+fp16 (96 blocks) + zero line-strided cnt
// (1563 blocks, 6.4 MB). cnt[node*16]: ONE counter per 64B line so the
// atomic RMW same-line serialization is 10-way (per node), not 160-way
// (per 16-node line).
// ---------------------------------------------------------------------------
__global__ __launch_bounds__(256) void prep_zero_kernel(
    const float* __restrict__ qw, const float* __restrict__ kw,
    const float* __restrict__ vw, const float* __restrict__ ow,
    _Float16* __restrict__ WqT, _Float16* __restrict__ WkT,
    _Float16* __restrict__ WvT, _Float16* __restrict__ WoT,
    int* __restrict__ cnt)
{
    if (blockIdx.x < PREP_BLOCKS) {
        const int idx = blockIdx.x * 256 + threadIdx.x;   // 0..24575
        if (idx < 8192) {
            const int c = idx >> 7, k = idx & 127;
            WqT[idx] = (_Float16)qw[k * 64 + c];
        } else if (idx < 16384) {
            const int i = idx - 8192, c = i >> 7, k = i & 127;
            WkT[i] = (_Float16)kw[k * 64 + c];
        } else if (idx < 20480) {
            const int i = idx - 16384, c = i >> 6, k = i & 63;
            WvT[i] = (_Float16)vw[k * 64 + c];
        } else {
            const int i = idx - 20480, c = i >> 6, k = i & 63;
            WoT[i] = (_Float16)ow[k * 64 + c];
        }
    } else {
        const int idx = (blockIdx.x - PREP_BLOCKS) * 256 + threadIdx.x;
        if (idx < N_NODES * 4)                  // 1.6M ints as int4
            ((int4*)cnt)[idx] = make_int4(0, 0, 0, 0);
    }
}

// ---------------------------------------------------------------------------
// Dispatch 2: QKV-MFMA (1563 blocks first) || fill (3907 blocks, 1 edge per
// thread for max memory-level parallelism; line-strided counters).
// qkv: block = 64 nodes, 4 waves; wave w owns col tile w of Q, K, V.
// A-tile [64][128] f16 LDS, group j of row r stored at j^(r&15).
// Layouts (m89-verified): A row=lane&15, k=(lane>>4)*8+j ; B col=lane&15,
// same k ; D col=lane&15, row=(lane>>4)*4+reg. Q now stored fp16 (Qh).
// ---------------------------------------------------------------------------
__global__ __launch_bounds__(256) void fill_qkv_kernel(
    const int* __restrict__ src, const int* __restrict__ dst,
    int* __restrict__ cnt, int* __restrict__ csr_src,
    const float* __restrict__ x, const float* __restrict__ tf,
    const _Float16* __restrict__ WqT, const _Float16* __restrict__ WkT,
    const _Float16* __restrict__ WvT,
    const float* __restrict__ qb, const float* __restrict__ kb,
    const float* __restrict__ vb,
    _Float16* __restrict__ Qh, _Float16* __restrict__ Kh,
    _Float16* __restrict__ Vh)
{
    __shared__ _Float16 xt[64][128];     // 16 KB (fill blocks ignore it)
    const int t = threadIdx.x;

    if (blockIdx.x >= QKV_BLOCKS) {
        const int e = (blockIdx.x - QKV_BLOCKS) * 256 + t;
        if (e < N_EDGES) {
            const int d  = dst[e];
            const int sv = src[e];
            const int pos = atomicAdd(&cnt[(size_t)d * 16], 1);
            if (pos < SLOTS) csr_src[(size_t)d * SLOTS + pos] = sv;
        }
        return;
    }

    const int base = blockIdx.x * 64;

    // stage [x|tf] -> LDS f16, swizzled groups
    {
        const int j = t & 15;
        #pragma unroll
        for (int i = 0; i < 4; ++i) {
            const int r = (t >> 4) + 16 * i;
            int node = base + r;
            if (node >= N_NODES) node = N_NODES - 1;   // clamp; stores guarded
            const float* p = (j < 8) ? (x  + (size_t)node * 64 + 8 * j)
                                     : (tf + (size_t)node * 64 + 8 * (j - 8));
            const float4 lo = ((const float4*)p)[0];
            const float4 hi = ((const float4*)p)[1];
            f16x8 h = { (_Float16)lo.x, (_Float16)lo.y, (_Float16)lo.z,
                        (_Float16)lo.w, (_Float16)hi.x, (_Float16)hi.y,
                        (_Float16)hi.z, (_Float16)hi.w };
            const int js = j ^ (r & 15);
            *(f16x8*)&xt[r][js * 8] = h;
        }
    }

    const int wave = t >> 6;
    const int lane = t & 63;
    const int lrow = lane & 15;
    const int lgrp = lane >> 4;
    const int cw   = wave * 16;

    f16x8 bq[4], bk[4], bv[2];
    const float biasq = qb[cw + lrow];
    const float biask = kb[cw + lrow];
    const float biasv = vb[cw + lrow];
    {
        const size_t rq = (size_t)(cw + lrow) * 128 + lgrp * 8;
        #pragma unroll
        for (int kt = 0; kt < 4; ++kt) {
            bq[kt] = *(const f16x8*)&WqT[rq + kt * 32];
            bk[kt] = *(const f16x8*)&WkT[rq + kt * 32];
        }
        const size_t rv = (size_t)(cw + lrow) * 64 + lgrp * 8;
        #pragma unroll
        for (int kt = 0; kt < 2; ++kt)
            bv[kt] = *(const f16x8*)&WvT[rv + kt * 32];
    }
    __syncthreads();

    #pragma unroll
    for (int rt = 0; rt < 4; ++rt) {
        f16x8 a[4];
        const int r = rt * 16 + lrow;
        #pragma unroll
        for (int kt = 0; kt < 4; ++kt) {
            const int js = (kt * 4 + lgrp) ^ lrow;
            a[kt] = *(const f16x8*)&xt[r][js * 8];
        }
        f32x4 accq = {0.f, 0.f, 0.f, 0.f};
        f32x4 acck = {0.f, 0.f, 0.f, 0.f};
        f32x4 accv = {0.f, 0.f, 0.f, 0.f};
        #pragma unroll
        for (int kt = 0; kt < 4; ++kt) {
            accq = __builtin_amdgcn_mfma_f32_16x16x32_f16(a[kt], bq[kt], accq, 0, 0, 0);
            acck = __builtin_amdgcn_mfma_f32_16x16x32_f16(a[kt], bk[kt], acck, 0, 0, 0);
        }
        #pragma unroll
        for (int kt = 0; kt < 2; ++kt)
            accv = __builtin_amdgcn_mfma_f32_16x16x32_f16(a[kt], bv[kt], accv, 0, 0, 0);
        #pragma unroll
        for (int rr = 0; rr < 4; ++rr) {
            const int node = base + rt * 16 + lgrp * 4 + rr;
            if (node < N_NODES) {
                const size_t o = (size_t)node * 64 + cw + lrow;
                Qh[o] = (_Float16)(accq[rr] + biasq);
                Kh[o] = (_Float16)(acck[rr] + biask);
                Vh[o] = (_Float16)(accv[rr] + biasv);
            }
        }
    }
}

// ---------------------------------------------------------------------------
// Dispatch 3: gather-aggregate + normalize + MFMA output GEMM, fused.
// Block = 16 nodes, 4 waves; wave processes 4 nodes sequentially (8-edge-slot
// loop, fp16 Q/K/V, 1-deep prefetch), normalized fp16 agg rows -> LDS
// (XOR-swizzled), then out[16x64] = aggh @ WoT via 2 MFMA per wave.
// CSR list for node n: csr_src[n*64 .. n*64+min(cnt[n*16],64)).
// ---------------------------------------------------------------------------
__global__ __launch_bounds__(256) void agg_kernel(
    const int* __restrict__ cnt, const int* __restrict__ csr_src,
    const __half* __restrict__ Qh, const __half* __restrict__ Kh,
    const __half* __restrict__ Vh,
    const _Float16* __restrict__ WoT, const float* __restrict__ ob,
    float* __restrict__ out)
{
    __shared__ _Float16 aggh[16][64];     // 2 KB
    const int wave = threadIdx.x >> 6;
    const int lane = threadIdx.x & 63;
    const int g    = lane >> 3;        // edge slot 0..7
    const int s    = lane & 7;         // sublane: cols 8s..8s+7
    const int lrow = lane & 15;        // MFMA A-row / D-col
    const int lgrp = lane >> 4;        // MFMA k-group
    const int nb   = blockIdx.x * 16;  // grid exact: 6250*16

    f16x8 bo0, bo1;
    {
        const size_t ro = (size_t)(wave * 16 + lrow) * 64 + lgrp * 8;
        bo0 = *(const f16x8*)&WoT[ro];
        bo1 = *(const f16x8*)&WoT[ro + 32];
    }
    const float biaso = ob[wave * 16 + lrow];

    const uint4* __restrict__ Q4 = (const uint4*)Qh;
    const uint4* __restrict__ K4 = (const uint4*)Kh;
    const uint4* __restrict__ V4 = (const uint4*)Vh;

    for (int nn = 0; nn < 4; ++nn) {
        const int node = nb + wave * 4 + nn;
        // unpack this node's Q slice (cols 8s..8s+7) once
        float qf[8];
        {
            const uint4 qu = Q4[(size_t)node * 8 + s];
            const __half2* qh = (const __half2*)&qu;
            #pragma unroll
            for (int j = 0; j < 4; ++j) {
                const float2 a = __half22float2(qh[j]);
                qf[2 * j] = a.x; qf[2 * j + 1] = a.y;
            }
        }
        int d = cnt[(size_t)node * 16];
        if (d > SLOTS) d = SLOTS;
        const int lo = node * SLOTS;
        const int hi = lo + d;

        float acc[8] = {0.f, 0.f, 0.f, 0.f, 0.f, 0.f, 0.f, 0.f};
        float ssum = 0.f;

        if (lo < hi) {
            int base = lo;
            const int e0 = base + g;
            const int i0 = csr_src[(e0 < hi) ? e0 : (hi - 1)];
            bool act = (e0 < hi);
            uint4 ku = K4[(size_t)i0 * 8 + s];
            uint4 vu = V4[(size_t)i0 * 8 + s];

            while (base < hi) {
                const int nbase = base + 8;
                uint4 kn = make_uint4(0u, 0u, 0u, 0u);
                uint4 vn = make_uint4(0u, 0u, 0u, 0u);
                bool actn = false;
                if (nbase < hi) {                 // prefetch next 8-edge batch
                    const int en = nbase + g;
                    const int in_ = csr_src[(en < hi) ? en : (hi - 1)];
                    kn = K4[(size_t)in_ * 8 + s];
                    vn = V4[(size_t)in_ * 8 + s];
                    actn = (en < hi);
                }
                float kf[8], vf[8];
                {
                    const __half2* kh = (const __half2*)&ku;
                    const __half2* vh = (const __half2*)&vu;
                    #pragma unroll
                    for (int j = 0; j < 4; ++j) {
                        const float2 a = __half22float2(kh[j]);
                        const float2 b = __half22float2(vh[j]);
                        kf[2 * j] = a.x; kf[2 * j + 1] = a.y;
                        vf[2 * j] = b.x; vf[2 * j + 1] = b.y;
                    }
                }
                float dq = qf[0] * kf[0] + qf[1] * kf[1] + qf[2] * kf[2] + qf[3] * kf[3]
                         + qf[4] * kf[4] + qf[5] * kf[5] + qf[6] * kf[6] + qf[7] * kf[7];
                dq += __shfl_xor(dq, 1);          // pair (2h,2h+1): full head dot
                const float p = act ? __expf(dq * 0.25f) : 0.f;   // 1/sqrt(16)
                ssum += p;
                #pragma unroll
                for (int j = 0; j < 8; ++j) acc[j] = fmaf(p, vf[j], acc[j]);
                ku = kn; vu = vn; act = actn; base = nbase;
            }
        }

        // combine the 8 edge slots (lane bits 3,4,5)
        #pragma unroll
        for (int m = 8; m <= 32; m <<= 1) {
            #pragma unroll
            for (int j = 0; j < 8; ++j) acc[j] += __shfl_xor(acc[j], m);
            ssum += __shfl_xor(ssum, m);
        }

        const float inv = (ssum > 0.f) ? (1.0f / ssum) : 0.0f;
        if (g == 0) {
            const int r = wave * 4 + nn;
            f16x8 h = { (_Float16)(acc[0] * inv), (_Float16)(acc[1] * inv),
                        (_Float16)(acc[2] * inv), (_Float16)(acc[3] * inv),
                        (_Float16)(acc[4] * inv), (_Float16)(acc[5] * inv),
                        (_Float16)(acc[6] * inv), (_Float16)(acc[7] * inv) };
            *(f16x8*)&aggh[r][(s ^ (r & 7)) * 8] = h;   // swizzled group
        }
    }
    __syncthreads();

    // out tile [16 nodes][64 cols] = aggh @ WoT ; wave w -> cols 16w..16w+15
    f16x8 a0, a1;
    {
        const int p0 = (lgrp)     ^ (lrow & 7);
        const int p1 = (4 + lgrp) ^ (lrow & 7);
        a0 = *(const f16x8*)&aggh[lrow][p0 * 8];
        a1 = *(const f16x8*)&aggh[lrow][p1 * 8];
    }
    f32x4 acco = {0.f, 0.f, 0.f, 0.f};
    acco = __builtin_amdgcn_mfma_f32_16x16x32_f16(a0, bo0, acco, 0, 0, 0);
    acco = __builtin_amdgcn_mfma_f32_16x16x32_f16(a1, bo1, acco, 0, 0, 0);
    #pragma unroll
    for (int rr = 0; rr < 4; ++rr) {
        const int node = nb + lgrp * 4 + rr;      // D row = lgrp*4+rr
        out[(size_t)node * 64 + wave * 16 + lrow] = acco[rr] + biaso;
    }
}

// ---------------------------------------------------------------------------
extern "C" void kernel_launch(void* const* d_in, const int* in_sizes, int n_in,
                              void* d_out, int out_size, void* d_ws, size_t ws_size,
                              hipStream_t stream) {
    const float* x  = (const float*)d_in[0];
    const float* tf = (const float*)d_in[1];
    const int*   ei = (const int*)  d_in[2];
    const float* qw = (const float*)d_in[3];
    const float* qb = (const float*)d_in[4];
    const float* kw = (const float*)d_in[5];
    const float* kb = (const float*)d_in[6];
    const float* vw = (const float*)d_in[7];
    const float* vb = (const float*)d_in[8];
    const float* ow = (const float*)d_in[9];
    const float* ob = (const float*)d_in[10];
    float* out = (float*)d_out;

    char* ws = (char*)d_ws;
    const size_t hf = (size_t)N_NODES * 64 * sizeof(_Float16);  // 12.8 MB

    _Float16* Qh      = (_Float16*)(ws);
    _Float16* Kh      = (_Float16*)(ws + hf);
    _Float16* Vh      = (_Float16*)(ws + 2 * hf);
    _Float16* WqT     = (_Float16*)(ws + 3 * hf);        // 8192 halves
    _Float16* WkT     = WqT + 8192;                       // 8192
    _Float16* WvT     = WkT + 8192;                       // 4096
    _Float16* WoT     = WvT + 4096;                       // 4096
    int*      cnt     = (int*)(WoT + 4096);               // 100000*16 ints (6.4 MB)
    int*      csr_src = cnt + (size_t)N_NODES * 16;       // 100000*64 ints

    const int* src = ei;             // edge_index[0]
    const int* dst = ei + N_EDGES;   // edge_index[1]

    const dim3 blk(256);
    prep_zero_kernel<<<dim3(PREP_BLOCKS + ZERO_BLOCKS), blk, 0, stream>>>(
        qw, kw, vw, ow, WqT, WkT, WvT, WoT, cnt);

    fill_qkv_kernel<<<dim3(QKV_BLOCKS + FILL_BLOCKS), blk, 0, stream>>>(
        src, dst, cnt, csr_src,
        x, tf, WqT, WkT, WvT, qb, kb, vb, Qh, Kh, Vh);

    agg_kernel<<<dim3(AGG_BLOCKS), blk, 0, stream>>>(
        cnt, csr_src, (const __half*)Qh, (const __half*)Kh, (const __half*)Vh,
        WoT, ob, out);
}

// Round 13
// 142.142 us; speedup vs baseline: 1.1433x; 1.1257x over previous
//
#include <hip/hip_runtime.h>
#include <hip/hip_fp16.h>
#include <math.h>

#define N_NODES 100000
#define N_EDGES 1000000
#define QKV_BLOCKS ((N_NODES + 63) / 64)      // 1563
#define FILL_BLOCKS ((N_EDGES + 255) / 256)   // 3907 (1 edge/thread)
#define PREP_BLOCKS 96                        // 24576 weight elems / 256
#define HEAD_INT4 ((N_NODES * 8) / 4)         // 200000 int4 stores
#define ZERO_BLOCKS ((HEAD_INT4 + 255) / 256) // 782
#define AGG_BLOCKS (N_NODES / 16)             // 6250
// IN=64, TD=64, OUT=64, H=4, HD=16

typedef __attribute__((ext_vector_type(8))) _Float16 f16x8;
typedef __attribute__((ext_vector_type(4))) float    f32x4;

// ---------------------------------------------------------------------------
// Dispatch 1: weight transpose+fp16 (96 blocks) + init head[] = -1 (782
// blocks, 3.2 MB). 8 list-heads per node (one per agg edge-slot).
// ---------------------------------------------------------------------------
__global__ __launch_bounds__(256) void prep_zero_kernel(
    const float* __restrict__ qw, const float* __restrict__ kw,
    const float* __restrict__ vw, const float* __restrict__ ow,
    _Float16* __restrict__ WqT, _Float16* __restrict__ WkT,
    _Float16* __restrict__ WvT, _Float16* __restrict__ WoT,
    int* __restrict__ head)
{
    if (blockIdx.x < PREP_BLOCKS) {
        const int idx = blockIdx.x * 256 + threadIdx.x;   // 0..24575
        if (idx < 8192) {
            const int c = idx >> 7, k = idx & 127;
            WqT[idx] = (_Float16)qw[k * 64 + c];
        } else if (idx < 16384) {
            const int i = idx - 8192, c = i >> 7, k = i & 127;
            WkT[i] = (_Float16)kw[k * 64 + c];
        } else if (idx < 20480) {
            const int i = idx - 16384, c = i >> 6, k = i & 63;
            WvT[i] = (_Float16)vw[k * 64 + c];
        } else {
            const int i = idx - 20480, c = i >> 6, k = i & 63;
            WoT[i] = (_Float16)ow[k * 64 + c];
        }
    } else {
        const int idx = (blockIdx.x - PREP_BLOCKS) * 256 + threadIdx.x;
        if (idx < HEAD_INT4)
            ((int4*)head)[idx] = make_int4(-1, -1, -1, -1);
    }
}

// ---------------------------------------------------------------------------
// Dispatch 2: QKV-MFMA (1563 blocks) || linked-list fill (3907 blocks).
// fill: old = atomicExch(&head[d*8+(e&7)], e)  -- 3.2 MB L2-resident atomics;
//       next2[e] = {old, src[e]}               -- COALESCED 8B store.
// No scattered 4B stores -> no partial-line RFO/writeback amplification
// (round-12 falsified line-contention; WRITE_SIZE showed 17x amplification).
// qkv: unchanged m89-verified MFMA structure, fp16 Q/K/V outputs.
// ---------------------------------------------------------------------------
__global__ __launch_bounds__(256) void fill_qkv_kernel(
    const int* __restrict__ src, const int* __restrict__ dst,
    int* __restrict__ head, int2* __restrict__ next2,
    const float* __restrict__ x, const float* __restrict__ tf,
    const _Float16* __restrict__ WqT, const _Float16* __restrict__ WkT,
    const _Float16* __restrict__ WvT,
    const float* __restrict__ qb, const float* __restrict__ kb,
    const float* __restrict__ vb,
    _Float16* __restrict__ Qh, _Float16* __restrict__ Kh,
    _Float16* __restrict__ Vh)
{
    __shared__ _Float16 xt[64][128];     // 16 KB (fill blocks ignore it)
    const int t = threadIdx.x;

    if (blockIdx.x >= QKV_BLOCKS) {
        const int e = (blockIdx.x - QKV_BLOCKS) * 256 + t;
        if (e < N_EDGES) {
            const int d  = dst[e];
            const int sv = src[e];
            const int old = atomicExch(&head[(size_t)d * 8 + (e & 7)], e);
            next2[e] = make_int2(old, sv);
        }
        return;
    }

    const int base = blockIdx.x * 64;

    // stage [x|tf] -> LDS f16, swizzled groups
    {
        const int j = t & 15;
        #pragma unroll
        for (int i = 0; i < 4; ++i) {
            const int r = (t >> 4) + 16 * i;
            int node = base + r;
            if (node >= N_NODES) node = N_NODES - 1;   // clamp; stores guarded
            const float* p = (j < 8) ? (x  + (size_t)node * 64 + 8 * j)
                                     : (tf + (size_t)node * 64 + 8 * (j - 8));
            const float4 lo = ((const float4*)p)[0];
            const float4 hi = ((const float4*)p)[1];
            f16x8 h = { (_Float16)lo.x, (_Float16)lo.y, (_Float16)lo.z,
                        (_Float16)lo.w, (_Float16)hi.x, (_Float16)hi.y,
                        (_Float16)hi.z, (_Float16)hi.w };
            const int js = j ^ (r & 15);
            *(f16x8*)&xt[r][js * 8] = h;
        }
    }

    const int wave = t >> 6;
    const int lane = t & 63;
    const int lrow = lane & 15;
    const int lgrp = lane >> 4;
    const int cw   = wave * 16;

    f16x8 bq[4], bk[4], bv[2];
    const float biasq = qb[cw + lrow];
    const float biask = kb[cw + lrow];
    const float biasv = vb[cw + lrow];
    {
        const size_t rq = (size_t)(cw + lrow) * 128 + lgrp * 8;
        #pragma unroll
        for (int kt = 0; kt < 4; ++kt) {
            bq[kt] = *(const f16x8*)&WqT[rq + kt * 32];
            bk[kt] = *(const f16x8*)&WkT[rq + kt * 32];
        }
        const size_t rv = (size_t)(cw + lrow) * 64 + lgrp * 8;
        #pragma unroll
        for (int kt = 0; kt < 2; ++kt)
            bv[kt] = *(const f16x8*)&WvT[rv + kt * 32];
    }
    __syncthreads();

    #pragma unroll
    for (int rt = 0; rt < 4; ++rt) {
        f16x8 a[4];
        const int r = rt * 16 + lrow;
        #pragma unroll
        for (int kt = 0; kt < 4; ++kt) {
            const int js = (kt * 4 + lgrp) ^ lrow;
            a[kt] = *(const f16x8*)&xt[r][js * 8];
        }
        f32x4 accq = {0.f, 0.f, 0.f, 0.f};
        f32x4 acck = {0.f, 0.f, 0.f, 0.f};
        f32x4 accv = {0.f, 0.f, 0.f, 0.f};
        #pragma unroll
        for (int kt = 0; kt < 4; ++kt) {
            accq = __builtin_amdgcn_mfma_f32_16x16x32_f16(a[kt], bq[kt], accq, 0, 0, 0);
            acck = __builtin_amdgcn_mfma_f32_16x16x32_f16(a[kt], bk[kt], acck, 0, 0, 0);
        }
        #pragma unroll
        for (int kt = 0; kt < 2; ++kt)
            accv = __builtin_amdgcn_mfma_f32_16x16x32_f16(a[kt], bv[kt], accv, 0, 0, 0);
        #pragma unroll
        for (int rr = 0; rr < 4; ++rr) {
            const int node = base + rt * 16 + lgrp * 4 + rr;
            if (node < N_NODES) {
                const size_t o = (size_t)node * 64 + cw + lrow;
                Qh[o] = (_Float16)(accq[rr] + biasq);
                Kh[o] = (_Float16)(acck[rr] + biask);
                Vh[o] = (_Float16)(accv[rr] + biasv);
            }
        }
    }
}

// ---------------------------------------------------------------------------
// Dispatch 3: gather-aggregate + normalize + MFMA output GEMM, fused.
// Block = 16 nodes, 4 waves; wave processes 4 nodes sequentially. Slot g
// (lane>>3) walks the node's sub-chain g: e = head[n*8+g]; per hop one
// broadcast int2 read {next, src} then K/V gather. Exp-weighted accumulate,
// slot-combine via shfl, normalized fp16 agg rows -> LDS (XOR-swizzled),
// then out[16x64] = aggh @ WoT via 2 MFMA per wave.
// ---------------------------------------------------------------------------
__global__ __launch_bounds__(256) void agg_kernel(
    const int* __restrict__ head, const int2* __restrict__ next2,
    const __half* __restrict__ Qh, const __half* __restrict__ Kh,
    const __half* __restrict__ Vh,
    const _Float16* __restrict__ WoT, const float* __restrict__ ob,
    float* __restrict__ out)
{
    __shared__ _Float16 aggh[16][64];     // 2 KB
    const int wave = threadIdx.x >> 6;
    const int lane = threadIdx.x & 63;
    const int g    = lane >> 3;        // edge slot / sub-chain 0..7
    const int s    = lane & 7;         // sublane: cols 8s..8s+7
    const int lrow = lane & 15;        // MFMA A-row / D-col
    const int lgrp = lane >> 4;        // MFMA k-group
    const int nb   = blockIdx.x * 16;  // grid exact: 6250*16

    f16x8 bo0, bo1;
    {
        const size_t ro = (size_t)(wave * 16 + lrow) * 64 + lgrp * 8;
        bo0 = *(const f16x8*)&WoT[ro];
        bo1 = *(const f16x8*)&WoT[ro + 32];
    }
    const float biaso = ob[wave * 16 + lrow];

    const uint4* __restrict__ Q4 = (const uint4*)Qh;
    const uint4* __restrict__ K4 = (const uint4*)Kh;
    const uint4* __restrict__ V4 = (const uint4*)Vh;

    for (int nn = 0; nn < 4; ++nn) {
        const int node = nb + wave * 4 + nn;
        // unpack this node's Q slice (cols 8s..8s+7) once
        float qf[8];
        {
            const uint4 qu = Q4[(size_t)node * 8 + s];
            const __half2* qh = (const __half2*)&qu;
            #pragma unroll
            for (int j = 0; j < 4; ++j) {
                const float2 a = __half22float2(qh[j]);
                qf[2 * j] = a.x; qf[2 * j + 1] = a.y;
            }
        }

        float acc[8] = {0.f, 0.f, 0.f, 0.f, 0.f, 0.f, 0.f, 0.f};
        float ssum = 0.f;

        int e = head[(size_t)node * 8 + g];      // broadcast within slot
        bool act = (e >= 0);
        while (__any(act)) {
            const int es = act ? e : 0;
            const int2 sn = next2[es];           // {next, src}, broadcast 8B
            const int sv = sn.y;
            const uint4 ku = K4[(size_t)sv * 8 + s];
            const uint4 vu = V4[(size_t)sv * 8 + s];

            float kf[8], vf[8];
            {
                const __half2* kh = (const __half2*)&ku;
                const __half2* vh = (const __half2*)&vu;
                #pragma unroll
                for (int j = 0; j < 4; ++j) {
                    const float2 a = __half22float2(kh[j]);
                    const float2 b = __half22float2(vh[j]);
                    kf[2 * j] = a.x; kf[2 * j + 1] = a.y;
                    vf[2 * j] = b.x; vf[2 * j + 1] = b.y;
                }
            }
            float dq = qf[0] * kf[0] + qf[1] * kf[1] + qf[2] * kf[2] + qf[3] * kf[3]
                     + qf[4] * kf[4] + qf[5] * kf[5] + qf[6] * kf[6] + qf[7] * kf[7];
            dq += __shfl_xor(dq, 1);             // pair (2h,2h+1): full head dot
            const float p = act ? __expf(dq * 0.25f) : 0.f;   // 1/sqrt(16)
            ssum += p;
            #pragma unroll
            for (int j = 0; j < 8; ++j) acc[j] = fmaf(p, vf[j], acc[j]);

            e = act ? sn.x : -1;
            act = (e >= 0);
        }

        // combine the 8 slots (lane bits 3,4,5)
        #pragma unroll
        for (int m = 8; m <= 32; m <<= 1) {
            #pragma unroll
            for (int j = 0; j < 8; ++j) acc[j] += __shfl_xor(acc[j], m);
            ssum += __shfl_xor(ssum, m);
        }

        const float inv = (ssum > 0.f) ? (1.0f / ssum) : 0.0f;
        if (g == 0) {
            const int r = wave * 4 + nn;
            f16x8 h = { (_Float16)(acc[0] * inv), (_Float16)(acc[1] * inv),
                        (_Float16)(acc[2] * inv), (_Float16)(acc[3] * inv),
                        (_Float16)(acc[4] * inv), (_Float16)(acc[5] * inv),
                        (_Float16)(acc[6] * inv), (_Float16)(acc[7] * inv) };
            *(f16x8*)&aggh[r][(s ^ (r & 7)) * 8] = h;   // swizzled group
        }
    }
    __syncthreads();

    // out tile [16 nodes][64 cols] = aggh @ WoT ; wave w -> cols 16w..16w+15
    f16x8 a0, a1;
    {
        const int p0 = (lgrp)     ^ (lrow & 7);
        const int p1 = (4 + lgrp) ^ (lrow & 7);
        a0 = *(const f16x8*)&aggh[lrow][p0 * 8];
        a1 = *(const f16x8*)&aggh[lrow][p1 * 8];
    }
    f32x4 acco = {0.f, 0.f, 0.f, 0.f};
    acco = __builtin_amdgcn_mfma_f32_16x16x32_f16(a0, bo0, acco, 0, 0, 0);
    acco = __builtin_amdgcn_mfma_f32_16x16x32_f16(a1, bo1, acco, 0, 0, 0);
    #pragma unroll
    for (int rr = 0; rr < 4; ++rr) {
        const int node = nb + lgrp * 4 + rr;      // D row = lgrp*4+rr
        out[(size_t)node * 64 + wave * 16 + lrow] = acco[rr] + biaso;
    }
}

// ---------------------------------------------------------------------------
extern "C" void kernel_launch(void* const* d_in, const int* in_sizes, int n_in,
                              void* d_out, int out_size, void* d_ws, size_t ws_size,
                              hipStream_t stream) {
    const float* x  = (const float*)d_in[0];
    const float* tf = (const float*)d_in[1];
    const int*   ei = (const int*)  d_in[2];
    const float* qw = (const float*)d_in[3];
    const float* qb = (const float*)d_in[4];
    const float* kw = (const float*)d_in[5];
    const float* kb = (const float*)d_in[6];
    const float* vw = (const float*)d_in[7];
    const float* vb = (const float*)d_in[8];
    const float* ow = (const float*)d_in[9];
    const float* ob = (const float*)d_in[10];
    float* out = (float*)d_out;

    char* ws = (char*)d_ws;
    const size_t hf = (size_t)N_NODES * 64 * sizeof(_Float16);  // 12.8 MB

    _Float16* Qh      = (_Float16*)(ws);
    _Float16* Kh      = (_Float16*)(ws + hf);
    _Float16* Vh      = (_Float16*)(ws + 2 * hf);
    _Float16* WqT     = (_Float16*)(ws + 3 * hf);        // 8192 halves
    _Float16* WkT     = WqT + 8192;                       // 8192
    _Float16* WvT     = WkT + 8192;                       // 4096
    _Float16* WoT     = WvT + 4096;                       // 4096
    int*      head    = (int*)(WoT + 4096);               // 100000*8 ints (3.2 MB)
    int2*     next2   = (int2*)(head + (size_t)N_NODES * 8);  // 1M int2 (8 MB)

    const int* src = ei;             // edge_index[0]
    const int* dst = ei + N_EDGES;   // edge_index[1]

    const dim3 blk(256);
    prep_zero_kernel<<<dim3(PREP_BLOCKS + ZERO_BLOCKS), blk, 0, stream>>>(
        qw, kw, vw, ow, WqT, WkT, WvT, WoT, head);

    fill_qkv_kernel<<<dim3(QKV_BLOCKS + FILL_BLOCKS), blk, 0, stream>>>(
        src, dst, head, next2,
        x, tf, WqT, WkT, WvT, qb, kb, vb, Qh, Kh, Vh);

    agg_kernel<<<dim3(AGG_BLOCKS), blk, 0, stream>>>(
        head, next2, (const __half*)Qh, (const __half*)Kh, (const __half*)Vh,
        WoT, ob, out);
}

// Round 14
// 140.889 us; speedup vs baseline: 1.1534x; 1.0089x over previous
//
#include <hip/hip_runtime.h>
#include <hip/hip_fp16.h>
#include <math.h>

#define N_NODES 100000
#define N_EDGES 1000000
#define QKV_BLOCKS ((N_NODES + 63) / 64)      // 1563
#define FILL_BLOCKS ((N_EDGES + 255) / 256)   // 3907 (1 edge/thread)
#define PREP_BLOCKS 96                        // 24576 weight elems / 256
#define AGG_BLOCKS (N_NODES / 32)             // 3125
// IN=64, TD=64, OUT=64, H=4, HD=16

typedef __attribute__((ext_vector_type(8))) _Float16 f16x8;
typedef __attribute__((ext_vector_type(4))) float    f32x4;

// ---------------------------------------------------------------------------
// Dispatch 1: weight transpose+fp16 (96 blocks). head[] init is a plain
// hipMemsetAsync(0xFF) = -1 (400 KB), no kernel needed.
// WqT/WkT: [64][128]; WvT/WoT: [64][64]. WT[c][k] = w[k*64+c].
// ---------------------------------------------------------------------------
__global__ __launch_bounds__(256) void prep_kernel(
    const float* __restrict__ qw, const float* __restrict__ kw,
    const float* __restrict__ vw, const float* __restrict__ ow,
    _Float16* __restrict__ WqT, _Float16* __restrict__ WkT,
    _Float16* __restrict__ WvT, _Float16* __restrict__ WoT)
{
    const int idx = blockIdx.x * 256 + threadIdx.x;   // 0..24575
    if (idx < 8192) {
        const int c = idx >> 7, k = idx & 127;
        WqT[idx] = (_Float16)qw[k * 64 + c];
    } else if (idx < 16384) {
        const int i = idx - 8192, c = i >> 7, k = i & 127;
        WkT[i] = (_Float16)kw[k * 64 + c];
    } else if (idx < 20480) {
        const int i = idx - 16384, c = i >> 6, k = i & 63;
        WvT[i] = (_Float16)vw[k * 64 + c];
    } else {
        const int i = idx - 20480, c = i >> 6, k = i & 63;
        WoT[i] = (_Float16)ow[k * 64 + c];
    }
}

// ---------------------------------------------------------------------------
// Dispatch 2: QKV-MFMA (1563 blocks) || linked-list fill (3907 blocks).
// fill: old = atomicExch(&head[d], e)  -- 400 KB region, ONE chain per node;
//       next2[e] = {old, src[e]}       -- coalesced 8B store. No scattered
// stores (r13 confirmed the write-amplification diagnosis; overlap works).
// qkv: m89-verified MFMA structure, fp16 Q/K/V outputs.
// ---------------------------------------------------------------------------
__global__ __launch_bounds__(256) void fill_qkv_kernel(
    const int* __restrict__ src, const int* __restrict__ dst,
    int* __restrict__ head, int2* __restrict__ next2,
    const float* __restrict__ x, const float* __restrict__ tf,
    const _Float16* __restrict__ WqT, const _Float16* __restrict__ WkT,
    const _Float16* __restrict__ WvT,
    const float* __restrict__ qb, const float* __restrict__ kb,
    const float* __restrict__ vb,
    _Float16* __restrict__ Qh, _Float16* __restrict__ Kh,
    _Float16* __restrict__ Vh)
{
    __shared__ _Float16 xt[64][128];     // 16 KB (fill blocks ignore it)
    const int t = threadIdx.x;

    if (blockIdx.x >= QKV_BLOCKS) {
        const int e = (blockIdx.x - QKV_BLOCKS) * 256 + t;
        if (e < N_EDGES) {
            const int d  = dst[e];
            const int sv = src[e];
            const int old = atomicExch(&head[d], e);
            next2[e] = make_int2(old, sv);
        }
        return;
    }

    const int base = blockIdx.x * 64;

    // stage [x|tf] -> LDS f16, swizzled groups
    {
        const int j = t & 15;
        #pragma unroll
        for (int i = 0; i < 4; ++i) {
            const int r = (t >> 4) + 16 * i;
            int node = base + r;
            if (node >= N_NODES) node = N_NODES - 1;   // clamp; stores guarded
            const float* p = (j < 8) ? (x  + (size_t)node * 64 + 8 * j)
                                     : (tf + (size_t)node * 64 + 8 * (j - 8));
            const float4 lo = ((const float4*)p)[0];
            const float4 hi = ((const float4*)p)[1];
            f16x8 h = { (_Float16)lo.x, (_Float16)lo.y, (_Float16)lo.z,
                        (_Float16)lo.w, (_Float16)hi.x, (_Float16)hi.y,
                        (_Float16)hi.z, (_Float16)hi.w };
            const int js = j ^ (r & 15);
            *(f16x8*)&xt[r][js * 8] = h;
        }
    }

    const int wave = t >> 6;
    const int lane = t & 63;
    const int lrow = lane & 15;
    const int lgrp = lane >> 4;
    const int cw   = wave * 16;

    f16x8 bq[4], bk[4], bv[2];
    const float biasq = qb[cw + lrow];
    const float biask = kb[cw + lrow];
    const float biasv = vb[cw + lrow];
    {
        const size_t rq = (size_t)(cw + lrow) * 128 + lgrp * 8;
        #pragma unroll
        for (int kt = 0; kt < 4; ++kt) {
            bq[kt] = *(const f16x8*)&WqT[rq + kt * 32];
            bk[kt] = *(const f16x8*)&WkT[rq + kt * 32];
        }
        const size_t rv = (size_t)(cw + lrow) * 64 + lgrp * 8;
        #pragma unroll
        for (int kt = 0; kt < 2; ++kt)
            bv[kt] = *(const f16x8*)&WvT[rv + kt * 32];
    }
    __syncthreads();

    #pragma unroll
    for (int rt = 0; rt < 4; ++rt) {
        f16x8 a[4];
        const int r = rt * 16 + lrow;
        #pragma unroll
        for (int kt = 0; kt < 4; ++kt) {
            const int js = (kt * 4 + lgrp) ^ lrow;
            a[kt] = *(const f16x8*)&xt[r][js * 8];
        }
        f32x4 accq = {0.f, 0.f, 0.f, 0.f};
        f32x4 acck = {0.f, 0.f, 0.f, 0.f};
        f32x4 accv = {0.f, 0.f, 0.f, 0.f};
        #pragma unroll
        for (int kt = 0; kt < 4; ++kt) {
            accq = __builtin_amdgcn_mfma_f32_16x16x32_f16(a[kt], bq[kt], accq, 0, 0, 0);
            acck = __builtin_amdgcn_mfma_f32_16x16x32_f16(a[kt], bk[kt], acck, 0, 0, 0);
        }
        #pragma unroll
        for (int kt = 0; kt < 2; ++kt)
            accv = __builtin_amdgcn_mfma_f32_16x16x32_f16(a[kt], bv[kt], accv, 0, 0, 0);
        #pragma unroll
        for (int rr = 0; rr < 4; ++rr) {
            const int node = base + rt * 16 + lgrp * 4 + rr;
            if (node < N_NODES) {
                const size_t o = (size_t)node * 64 + cw + lrow;
                Qh[o] = (_Float16)(accq[rr] + biasq);
                Kh[o] = (_Float16)(acck[rr] + biask);
                Vh[o] = (_Float16)(accv[rr] + biasv);
            }
        }
    }
}

// ---------------------------------------------------------------------------
// Dispatch 3: gather-aggregate + normalize + MFMA output GEMM, fused.
// Block = 32 nodes, 4 waves; wave handles EIGHT nodes in parallel: slot g
// (lane>>3) walks node (wave*8+g)'s single chain; sublane s (lane&7) owns
// cols 8s..8s+7 (head = s>>1). No cross-slot reduce: slot g's sublanes hold
// node g's full row; ssum per sublane is already its own head's sum.
// Then out[32x64] = aggh @ WoT via 2 row-tiles x 1 col-tile per wave (4 MFMA).
// ---------------------------------------------------------------------------
__global__ __launch_bounds__(256) void agg_kernel(
    const int* __restrict__ head, const int2* __restrict__ next2,
    const __half* __restrict__ Qh, const __half* __restrict__ Kh,
    const __half* __restrict__ Vh,
    const _Float16* __restrict__ WoT, const float* __restrict__ ob,
    float* __restrict__ out)
{
    __shared__ _Float16 aggh[32][64];     // 4 KB
    const int wave = threadIdx.x >> 6;
    const int lane = threadIdx.x & 63;
    const int g    = lane >> 3;        // node slot 0..7
    const int s    = lane & 7;         // sublane: cols 8s..8s+7
    const int lrow = lane & 15;        // MFMA A-row / D-col
    const int lgrp = lane >> 4;        // MFMA k-group
    const int cw   = wave * 16;        // out col tile base
    const int nb   = blockIdx.x * 32;  // grid exact: 3125*32
    const int node = nb + wave * 8 + g;

    // out-GEMM B-frags + bias up front
    f16x8 bo0, bo1;
    {
        const size_t ro = (size_t)(cw + lrow) * 64 + lgrp * 8;
        bo0 = *(const f16x8*)&WoT[ro];
        bo1 = *(const f16x8*)&WoT[ro + 32];
    }
    const float biaso = ob[cw + lrow];

    const uint4* __restrict__ Q4 = (const uint4*)Qh;
    const uint4* __restrict__ K4 = (const uint4*)Kh;
    const uint4* __restrict__ V4 = (const uint4*)Vh;

    // my node's Q slice (cols 8s..8s+7); 64 lanes = 8 rows coalesced
    float qf[8];
    {
        const uint4 qu = Q4[(size_t)node * 8 + s];
        const __half2* qh = (const __half2*)&qu;
        #pragma unroll
        for (int j = 0; j < 4; ++j) {
            const float2 a = __half22float2(qh[j]);
            qf[2 * j] = a.x; qf[2 * j + 1] = a.y;
        }
    }

    float acc[8] = {0.f, 0.f, 0.f, 0.f, 0.f, 0.f, 0.f, 0.f};
    float ssum = 0.f;

    int e = head[node];                  // slot-uniform within 8 sublanes
    bool act = (e >= 0);
    while (__any(act)) {
        const int es = act ? e : 0;
        const int2 sn = next2[es];       // {next, src}, broadcast 8B
        const int sv = sn.y;
        const uint4 ku = K4[(size_t)sv * 8 + s];
        const uint4 vu = V4[(size_t)sv * 8 + s];

        float kf[8], vf[8];
        {
            const __half2* kh = (const __half2*)&ku;
            const __half2* vh = (const __half2*)&vu;
            #pragma unroll
            for (int j = 0; j < 4; ++j) {
                const float2 a = __half22float2(kh[j]);
                const float2 b = __half22float2(vh[j]);
                kf[2 * j] = a.x; kf[2 * j + 1] = a.y;
                vf[2 * j] = b.x; vf[2 * j + 1] = b.y;
            }
        }
        float dq = qf[0] * kf[0] + qf[1] * kf[1] + qf[2] * kf[2] + qf[3] * kf[3]
                 + qf[4] * kf[4] + qf[5] * kf[5] + qf[6] * kf[6] + qf[7] * kf[7];
        dq += __shfl_xor(dq, 1);         // pair (2h,2h+1): full head dot
        const float p = act ? __expf(dq * 0.25f) : 0.f;   // 1/sqrt(16)
        ssum += p;
        #pragma unroll
        for (int j = 0; j < 8; ++j) acc[j] = fmaf(p, vf[j], acc[j]);

        e = act ? sn.x : -1;
        act = (e >= 0);
    }

    // normalize (ssum per sublane == its head's sum) and write row directly
    {
        const float inv = (ssum > 0.f) ? (1.0f / ssum) : 0.0f;
        const int r = wave * 8 + g;      // r & 7 == g
        f16x8 h = { (_Float16)(acc[0] * inv), (_Float16)(acc[1] * inv),
                    (_Float16)(acc[2] * inv), (_Float16)(acc[3] * inv),
                    (_Float16)(acc[4] * inv), (_Float16)(acc[5] * inv),
                    (_Float16)(acc[6] * inv), (_Float16)(acc[7] * inv) };
        *(f16x8*)&aggh[r][(s ^ g) * 8] = h;   // swizzled group
    }
    __syncthreads();

    // out tile [32 nodes][64 cols] = aggh @ WoT ; wave w -> cols 16w..16w+15,
    // row tiles rt=0 (nodes 0-15) and rt=1 (nodes 16-31).
    #pragma unroll
    for (int rt = 0; rt < 2; ++rt) {
        const int r = rt * 16 + lrow;    // r & 7 == lrow & 7
        f16x8 a0 = *(const f16x8*)&aggh[r][((lgrp)     ^ (lrow & 7)) * 8];
        f16x8 a1 = *(const f16x8*)&aggh[r][((4 + lgrp) ^ (lrow & 7)) * 8];
        f32x4 acco = {0.f, 0.f, 0.f, 0.f};
        acco = __builtin_amdgcn_mfma_f32_16x16x32_f16(a0, bo0, acco, 0, 0, 0);
        acco = __builtin_amdgcn_mfma_f32_16x16x32_f16(a1, bo1, acco, 0, 0, 0);
        #pragma unroll
        for (int rr = 0; rr < 4; ++rr) {
            const int n = nb + rt * 16 + lgrp * 4 + rr;   // D row = lgrp*4+rr
            out[(size_t)n * 64 + cw + lrow] = acco[rr] + biaso;
        }
    }
}

// ---------------------------------------------------------------------------
extern "C" void kernel_launch(void* const* d_in, const int* in_sizes, int n_in,
                              void* d_out, int out_size, void* d_ws, size_t ws_size,
                              hipStream_t stream) {
    const float* x  = (const float*)d_in[0];
    const float* tf = (const float*)d_in[1];
    const int*   ei = (const int*)  d_in[2];
    const float* qw = (const float*)d_in[3];
    const float* qb = (const float*)d_in[4];
    const float* kw = (const float*)d_in[5];
    const float* kb = (const float*)d_in[6];
    const float* vw = (const float*)d_in[7];
    const float* vb = (const float*)d_in[8];
    const float* ow = (const float*)d_in[9];
    const float* ob = (const float*)d_in[10];
    float* out = (float*)d_out;

    char* ws = (char*)d_ws;
    const size_t hf = (size_t)N_NODES * 64 * sizeof(_Float16);  // 12.8 MB

    _Float16* Qh      = (_Float16*)(ws);
    _Float16* Kh      = (_Float16*)(ws + hf);
    _Float16* Vh      = (_Float16*)(ws + 2 * hf);
    _Float16* WqT     = (_Float16*)(ws + 3 * hf);        // 8192 halves
    _Float16* WkT     = WqT + 8192;                       // 8192
    _Float16* WvT     = WkT + 8192;                       // 4096
    _Float16* WoT     = WvT + 4096;                       // 4096
    int*      head    = (int*)(WoT + 4096);               // 100000 ints (400 KB)
    int2*     next2   = (int2*)(head + N_NODES);          // 1M int2 (8 MB)

    const int* src = ei;             // edge_index[0]
    const int* dst = ei + N_EDGES;   // edge_index[1]

    const dim3 blk(256);

    // head[] = -1 via byte-pattern memset; weights prep in parallel kernel
    hipMemsetAsync(head, 0xFF, N_NODES * sizeof(int), stream);

    prep_kernel<<<dim3(PREP_BLOCKS), blk, 0, stream>>>(
        qw, kw, vw, ow, WqT, WkT, WvT, WoT);

    fill_qkv_kernel<<<dim3(QKV_BLOCKS + FILL_BLOCKS), blk, 0, stream>>>(
        src, dst, head, next2,
        x, tf, WqT, WkT, WvT, qb, kb, vb, Qh, Kh, Vh);

    agg_kernel<<<dim3(AGG_BLOCKS), blk, 0, stream>>>(
        head, next2, (const __half*)Qh, (const __half*)Kh, (const __half*)Vh,
        WoT, ob, out);
}

// Round 15
// 131.824 us; speedup vs baseline: 1.2327x; 1.0688x over previous
//
#include <hip/hip_runtime.h>
#include <hip/hip_fp16.h>
#include <math.h>

#define N_NODES 100000
#define N_EDGES 1000000
#define QKV_BLOCKS ((N_NODES + 63) / 64)      // 1563
#define FILL_BLOCKS ((N_EDGES + 255) / 256)   // 3907 (1 edge/thread)
#define PREP_BLOCKS 96                        // 24576 weight elems / 256
#define AGG_BLOCKS ((N_NODES + 63) / 64)      // 1563 (64 nodes/block)
// IN=64, TD=64, OUT=64, H=4, HD=16

typedef __attribute__((ext_vector_type(8))) _Float16 f16x8;
typedef __attribute__((ext_vector_type(4))) float    f32x4;

// ---------------------------------------------------------------------------
// Dispatch 1: weight transpose+fp16 (96 blocks). head[] init via memset 0xFF.
// WqT/WkT: [64][128]; WvT/WoT: [64][64]. WT[c][k] = w[k*64+c].
// ---------------------------------------------------------------------------
__global__ __launch_bounds__(256) void prep_kernel(
    const float* __restrict__ qw, const float* __restrict__ kw,
    const float* __restrict__ vw, const float* __restrict__ ow,
    _Float16* __restrict__ WqT, _Float16* __restrict__ WkT,
    _Float16* __restrict__ WvT, _Float16* __restrict__ WoT)
{
    const int idx = blockIdx.x * 256 + threadIdx.x;   // 0..24575
    if (idx < 8192) {
        const int c = idx >> 7, k = idx & 127;
        WqT[idx] = (_Float16)qw[k * 64 + c];
    } else if (idx < 16384) {
        const int i = idx - 8192, c = i >> 7, k = i & 127;
        WkT[i] = (_Float16)kw[k * 64 + c];
    } else if (idx < 20480) {
        const int i = idx - 16384, c = i >> 6, k = i & 63;
        WvT[i] = (_Float16)vw[k * 64 + c];
    } else {
        const int i = idx - 20480, c = i >> 6, k = i & 63;
        WoT[i] = (_Float16)ow[k * 64 + c];
    }
}

// ---------------------------------------------------------------------------
// Dispatch 2: QKV-MFMA (1563 blocks) || linked-list fill (3907 blocks).
// fill: old = atomicExch(&head[d], e); next2[e] = {old, src[e]} (coalesced).
// The ~70us cost is the device-scope returning-atomic wall (r11/r13 showed it
// is insensitive to address spread and op type); qkv hides beneath it.
// qkv: m89-verified MFMA; K/V now interleaved into KV[node][128] halves
// (K = cols 0..63, V = cols 64..127) for gather locality in agg.
// ---------------------------------------------------------------------------
__global__ __launch_bounds__(256) void fill_qkv_kernel(
    const int* __restrict__ src, const int* __restrict__ dst,
    int* __restrict__ head, int2* __restrict__ next2,
    const float* __restrict__ x, const float* __restrict__ tf,
    const _Float16* __restrict__ WqT, const _Float16* __restrict__ WkT,
    const _Float16* __restrict__ WvT,
    const float* __restrict__ qb, const float* __restrict__ kb,
    const float* __restrict__ vb,
    _Float16* __restrict__ Qh, _Float16* __restrict__ KV)
{
    __shared__ _Float16 xt[64][128];     // 16 KB (fill blocks ignore it)
    const int t = threadIdx.x;

    if (blockIdx.x >= QKV_BLOCKS) {
        const int e = (blockIdx.x - QKV_BLOCKS) * 256 + t;
        if (e < N_EDGES) {
            const int d  = dst[e];
            const int sv = src[e];
            const int old = atomicExch(&head[d], e);
            next2[e] = make_int2(old, sv);
        }
        return;
    }

    const int base = blockIdx.x * 64;

    // stage [x|tf] -> LDS f16, swizzled groups
    {
        const int j = t & 15;
        #pragma unroll
        for (int i = 0; i < 4; ++i) {
            const int r = (t >> 4) + 16 * i;
            int node = base + r;
            if (node >= N_NODES) node = N_NODES - 1;   // clamp; stores guarded
            const float* p = (j < 8) ? (x  + (size_t)node * 64 + 8 * j)
                                     : (tf + (size_t)node * 64 + 8 * (j - 8));
            const float4 lo = ((const float4*)p)[0];
            const float4 hi = ((const float4*)p)[1];
            f16x8 h = { (_Float16)lo.x, (_Float16)lo.y, (_Float16)lo.z,
                        (_Float16)lo.w, (_Float16)hi.x, (_Float16)hi.y,
                        (_Float16)hi.z, (_Float16)hi.w };
            const int js = j ^ (r & 15);
            *(f16x8*)&xt[r][js * 8] = h;
        }
    }

    const int wave = t >> 6;
    const int lane = t & 63;
    const int lrow = lane & 15;
    const int lgrp = lane >> 4;
    const int cw   = wave * 16;

    f16x8 bq[4], bk[4], bv[2];
    const float biasq = qb[cw + lrow];
    const float biask = kb[cw + lrow];
    const float biasv = vb[cw + lrow];
    {
        const size_t rq = (size_t)(cw + lrow) * 128 + lgrp * 8;
        #pragma unroll
        for (int kt = 0; kt < 4; ++kt) {
            bq[kt] = *(const f16x8*)&WqT[rq + kt * 32];
            bk[kt] = *(const f16x8*)&WkT[rq + kt * 32];
        }
        const size_t rv = (size_t)(cw + lrow) * 64 + lgrp * 8;
        #pragma unroll
        for (int kt = 0; kt < 2; ++kt)
            bv[kt] = *(const f16x8*)&WvT[rv + kt * 32];
    }
    __syncthreads();

    #pragma unroll
    for (int rt = 0; rt < 4; ++rt) {
        f16x8 a[4];
        const int r = rt * 16 + lrow;
        #pragma unroll
        for (int kt = 0; kt < 4; ++kt) {
            const int js = (kt * 4 + lgrp) ^ lrow;
            a[kt] = *(const f16x8*)&xt[r][js * 8];
        }
        f32x4 accq = {0.f, 0.f, 0.f, 0.f};
        f32x4 acck = {0.f, 0.f, 0.f, 0.f};
        f32x4 accv = {0.f, 0.f, 0.f, 0.f};
        #pragma unroll
        for (int kt = 0; kt < 4; ++kt) {
            accq = __builtin_amdgcn_mfma_f32_16x16x32_f16(a[kt], bq[kt], accq, 0, 0, 0);
            acck = __builtin_amdgcn_mfma_f32_16x16x32_f16(a[kt], bk[kt], acck, 0, 0, 0);
        }
        #pragma unroll
        for (int kt = 0; kt < 2; ++kt)
            accv = __builtin_amdgcn_mfma_f32_16x16x32_f16(a[kt], bv[kt], accv, 0, 0, 0);
        #pragma unroll
        for (int rr = 0; rr < 4; ++rr) {
            const int node = base + rt * 16 + lgrp * 4 + rr;
            if (node < N_NODES) {
                Qh[(size_t)node * 64 + cw + lrow]        = (_Float16)(accq[rr] + biasq);
                KV[(size_t)node * 128 + cw + lrow]       = (_Float16)(acck[rr] + biask);
                KV[(size_t)node * 128 + 64 + cw + lrow]  = (_Float16)(accv[rr] + biasv);
            }
        }
    }
}

// ---------------------------------------------------------------------------
// Dispatch 3: gather-aggregate + normalize + MFMA output GEMM, fused.
// Block = 64 nodes, 4 waves x 16 nodes. Work-pool load balancing: slot g
// (lane>>3) starts on node idx g; when its chain ends it flushes (normalize +
// write aggh row) and claims the next idx from an LDS ticket counter.
// Iterations/wave ~ sum(16 Poi(10))/8 + tail ~= 23 (vs max-of-8 = 2.08/node).
// Sublane s (lane&7) owns cols 8s..8s+7; ssum per sublane is its own head's
// sum (head = s>>1) -- no cross-slot reduce. Then out[64x64] = aggh @ WoT
// via 4 row-tiles x 2 MFMA per wave.
// ---------------------------------------------------------------------------
__global__ __launch_bounds__(256) void agg_kernel(
    const int* __restrict__ head, const int2* __restrict__ next2,
    const __half* __restrict__ Qh, const __half* __restrict__ KVh,
    const _Float16* __restrict__ WoT, const float* __restrict__ ob,
    float* __restrict__ out)
{
    __shared__ _Float16 aggh[64][64];     // 8 KB
    __shared__ int pool[4];
    const int t    = threadIdx.x;
    const int wave = t >> 6;
    const int lane = t & 63;
    const int g    = lane >> 3;        // slot 0..7
    const int s    = lane & 7;         // sublane: cols 8s..8s+7
    const int lrow = lane & 15;        // MFMA A-row / D-col
    const int lgrp = lane >> 4;        // MFMA k-group
    const int cw   = wave * 16;        // out col tile base
    const int nb   = blockIdx.x * 64;
    const int wbase = wave * 16;       // this wave's row base (rows wbase..wbase+15)

    if (lane == 0) pool[wave] = 8;     // idx 0..7 statically claimed by slots

    f16x8 bo0, bo1;
    {
        const size_t ro = (size_t)(cw + lrow) * 64 + lgrp * 8;
        bo0 = *(const f16x8*)&WoT[ro];
        bo1 = *(const f16x8*)&WoT[ro + 32];
    }
    const float biaso = ob[cw + lrow];
    __syncthreads();                   // pool init visible

    const uint4* __restrict__ Q4  = (const uint4*)Qh;
    const uint4* __restrict__ KV4 = (const uint4*)KVh;

    int   idx  = g;
    int   cur  = nb + wbase + idx;
    int   e    = (cur < N_NODES) ? head[cur] : -1;
    bool  done = false;
    float acc[8] = {0.f, 0.f, 0.f, 0.f, 0.f, 0.f, 0.f, 0.f};
    float ssum = 0.f;
    float qf[8];
    {
        const int qn = (cur < N_NODES) ? cur : 0;
        const uint4 qu = Q4[(size_t)qn * 8 + s];
        const __half2* qh = (const __half2*)&qu;
        #pragma unroll
        for (int j = 0; j < 4; ++j) {
            const float2 a = __half22float2(qh[j]);
            qf[2 * j] = a.x; qf[2 * j + 1] = a.y;
        }
    }

    for (;;) {
        // transition: flush finished node(s), claim next from the pool
        while (e < 0 && !done) {
            const float inv = (ssum > 0.f) ? (1.0f / ssum) : 0.0f;
            const int r = wbase + idx;
            f16x8 h = { (_Float16)(acc[0] * inv), (_Float16)(acc[1] * inv),
                        (_Float16)(acc[2] * inv), (_Float16)(acc[3] * inv),
                        (_Float16)(acc[4] * inv), (_Float16)(acc[5] * inv),
                        (_Float16)(acc[6] * inv), (_Float16)(acc[7] * inv) };
            *(f16x8*)&aggh[r][(s ^ (r & 7)) * 8] = h;

            int tkt = 0;
            if (s == 0) tkt = atomicAdd(&pool[wave], 1);
            tkt = __shfl(tkt, g * 8);                  // slot-uniform ticket
            if (tkt < 16) {
                idx = tkt;
                cur = nb + wbase + idx;
                e   = (cur < N_NODES) ? head[cur] : -1;
                const int qn = (cur < N_NODES) ? cur : 0;
                const uint4 qu = Q4[(size_t)qn * 8 + s];
                const __half2* qh = (const __half2*)&qu;
                #pragma unroll
                for (int j = 0; j < 4; ++j) {
                    const float2 a = __half22float2(qh[j]);
                    qf[2 * j] = a.x; qf[2 * j + 1] = a.y;
                }
                #pragma unroll
                for (int j = 0; j < 8; ++j) acc[j] = 0.f;
                ssum = 0.f;
            } else {
                done = true;
            }
        }
        if (__all(done)) break;

        const bool act = (e >= 0);
        const int  es  = act ? e : 0;
        const int2 sn  = next2[es];          // {next, src}
        const int  sv  = sn.y;
        const uint4 ku = KV4[(size_t)sv * 16 + s];       // K slice
        const uint4 vu = KV4[(size_t)sv * 16 + 8 + s];   // V slice (adjacent)

        float kf[8], vf[8];
        {
            const __half2* kh = (const __half2*)&ku;
            const __half2* vh = (const __half2*)&vu;
            #pragma unroll
            for (int j = 0; j < 4; ++j) {
                const float2 a = __half22float2(kh[j]);
                const float2 b = __half22float2(vh[j]);
                kf[2 * j] = a.x; kf[2 * j + 1] = a.y;
                vf[2 * j] = b.x; vf[2 * j + 1] = b.y;
            }
        }
        float dq = qf[0] * kf[0] + qf[1] * kf[1] + qf[2] * kf[2] + qf[3] * kf[3]
                 + qf[4] * kf[4] + qf[5] * kf[5] + qf[6] * kf[6] + qf[7] * kf[7];
        dq += __shfl_xor(dq, 1);             // pair (2h,2h+1): full head dot
        const float p = act ? __expf(dq * 0.25f) : 0.f;   // 1/sqrt(16)
        ssum += p;
        #pragma unroll
        for (int j = 0; j < 8; ++j) acc[j] = fmaf(p, vf[j], acc[j]);
        e = act ? sn.x : e;
    }
    __syncthreads();

    // out tile [64 nodes][64 cols] = aggh @ WoT ; wave w -> cols 16w..16w+15
    #pragma unroll
    for (int rt = 0; rt < 4; ++rt) {
        const int r = rt * 16 + lrow;        // r & 7 == lrow & 7
        f16x8 a0 = *(const f16x8*)&aggh[r][((lgrp)     ^ (lrow & 7)) * 8];
        f16x8 a1 = *(const f16x8*)&aggh[r][((4 + lgrp) ^ (lrow & 7)) * 8];
        f32x4 acco = {0.f, 0.f, 0.f, 0.f};
        acco = __builtin_amdgcn_mfma_f32_16x16x32_f16(a0, bo0, acco, 0, 0, 0);
        acco = __builtin_amdgcn_mfma_f32_16x16x32_f16(a1, bo1, acco, 0, 0, 0);
        #pragma unroll
        for (int rr = 0; rr < 4; ++rr) {
            const int n = nb + rt * 16 + lgrp * 4 + rr;   // D row = lgrp*4+rr
            if (n < N_NODES)
                out[(size_t)n * 64 + cw + lrow] = acco[rr] + biaso;
        }
    }
}

// ---------------------------------------------------------------------------
extern "C" void kernel_launch(void* const* d_in, const int* in_sizes, int n_in,
                              void* d_out, int out_size, void* d_ws, size_t ws_size,
                              hipStream_t stream) {
    const float* x  = (const float*)d_in[0];
    const float* tf = (const float*)d_in[1];
    const int*   ei = (const int*)  d_in[2];
    const float* qw = (const float*)d_in[3];
    const float* qb = (const float*)d_in[4];
    const float* kw = (const float*)d_in[5];
    const float* kb = (const float*)d_in[6];
    const float* vw = (const float*)d_in[7];
    const float* vb = (const float*)d_in[8];
    const float* ow = (const float*)d_in[9];
    const float* ob = (const float*)d_in[10];
    float* out = (float*)d_out;

    char* ws = (char*)d_ws;
    const size_t hf = (size_t)N_NODES * 64 * sizeof(_Float16);  // 12.8 MB

    _Float16* Qh      = (_Float16*)(ws);
    _Float16* KV      = (_Float16*)(ws + hf);            // 25.6 MB interleaved
    _Float16* WqT     = (_Float16*)(ws + 3 * hf);        // 8192 halves
    _Float16* WkT     = WqT + 8192;                       // 8192
    _Float16* WvT     = WkT + 8192;                       // 4096
    _Float16* WoT     = WvT + 4096;                       // 4096
    int*      head    = (int*)(WoT + 4096);               // 100000 ints (400 KB)
    int2*     next2   = (int2*)(head + N_NODES);          // 1M int2 (8 MB)

    const int* src = ei;             // edge_index[0]
    const int* dst = ei + N_EDGES;   // edge_index[1]

    const dim3 blk(256);

    hipMemsetAsync(head, 0xFF, N_NODES * sizeof(int), stream);  // head = -1

    prep_kernel<<<dim3(PREP_BLOCKS), blk, 0, stream>>>(
        qw, kw, vw, ow, WqT, WkT, WvT, WoT);

    fill_qkv_kernel<<<dim3(QKV_BLOCKS + FILL_BLOCKS), blk, 0, stream>>>(
        src, dst, head, next2,
        x, tf, WqT, WkT, WvT, qb, kb, vb, Qh, KV);

    agg_kernel<<<dim3(AGG_BLOCKS), blk, 0, stream>>>(
        head, next2, (const __half*)Qh, (const __half*)KV, WoT, ob, out);
}